// Round 4
// baseline (180.812 us; speedup 1.0000x reference)
//
#include <hip/hip_runtime.h>
#include <hip/hip_fp16.h>
#include <math.h>

// Capsule routing, fused, register-resident, fp16-staged.
// tid = j*32+ns. t[9]/ua[9] in registers; b never materialized
// (b[j,i] = ua·(x,1), rank-9 in x). x staged to LDS as half2 (k-paired,
// lane-stride-1, conflict-free b32 reads). Uacc mirrored in LDS stride-12
// for b128 phase-A reads. W/bias pre-converted to fp16 in d_ws (prologue)
// -> one 16B global load per d per phase. LDS 38.4 KB -> 4 blocks/CU.

#define BSZ   512
#define C_IN  256
#define HW    36
#define NS    32
#define NOC   10
#define OD    16
#define ROUTE 3
#define NIC   1152
#define NT    320
#define USTR  12

__global__ __launch_bounds__(256) void convert_w(
    const float* __restrict__ Wc, const float* __restrict__ bc,
    __half* __restrict__ w16)   // [40960 W | 5120 bias]
{
    const int n = 40960 + 5120;
    for (int i = blockIdx.x * 256 + threadIdx.x; i < n; i += gridDim.x * 256) {
        float v = (i < 40960) ? Wc[i] : bc[i - 40960];
        w16[i] = __float2half(v);
    }
}

__global__ __launch_bounds__(NT, 5) void caps_kernel(
    const float*  __restrict__ x,     // [BSZ, 256, 36] fp32
    const __half* __restrict__ w16,   // [5120, 8] fp16
    const __half* __restrict__ bc16,  // [5120] fp16
    float* __restrict__ out)          // [BSZ, 10, 16] fp32
{
    __shared__ __half2 xs2[4 * NIC];      // 18432 B: xs2[k2][p*32+ns], pair=(2k2,2k2+1)
    __shared__ float   stat2[NIC];        //  4608 B: logsumexp over j, idx p*32+ns
    __shared__ float   Ul[NOC*NS*USTR];   // 15360 B: Uacc mirror, row j*32+ns, b128-able
    // total 38400 B -> 4 blocks/CU (20 waves)

    const int tid = threadIdx.x;
    const float* xb = x + (size_t)blockIdx.x * (C_IN * HW);

    // ---- Stage x -> fp16 LDS. Task = (channel-pair c2, float4-col p4). ----
    for (int t = tid; t < 128 * 9; t += NT) {
        int c2 = t / 9, p4 = t % 9;
        float4 a = *(const float4*)(xb + (2 * c2) * HW + p4 * 4);
        float4 b = *(const float4*)(xb + (2 * c2 + 1) * HW + p4 * 4);
        int nsc = c2 >> 2, k2 = c2 & 3;
        int base = k2 * NIC + (p4 * 4) * 32 + nsc;
        xs2[base +  0] = __floats2half2_rn(a.x, b.x);
        xs2[base + 32] = __floats2half2_rn(a.y, b.y);
        xs2[base + 64] = __floats2half2_rn(a.z, b.z);
        xs2[base + 96] = __floats2half2_rn(a.w, b.w);
    }
    __syncthreads();

    const int j  = tid >> 5;    // 0..9  (wave-half uniform)
    const int ns = tid & 31;    // lane & 31

    const __half* wrow = w16 + (size_t)(ns * 160 + j * 16) * 8;  // 16 rows x 16 B
    float bcv[16];
    {
        const __half2* bb = (const __half2*)(bc16 + ns * 160 + j * 16);
        #pragma unroll
        for (int q = 0; q < 8; ++q) {
            float2 f = __half22float2(bb[q]);
            bcv[2 * q] = f.x; bcv[2 * q + 1] = f.y;
        }
    }

    float ua[9];   // cumulative routing coefficients (valid after it 0)

    for (int it = 0; it < ROUTE; ++it) {
        // ---- Phase A: stat2[i] = logsumexp_j ( Ul[j,ns_i]·(x_i,1) ) ----
        if (it > 0) {
            #pragma unroll
            for (int m = 0; m < 4; ++m) {
                int p = j + 10 * m;
                if (p < HW) {
                    int row = p * 32 + ns;
                    float xv[8];
                    #pragma unroll
                    for (int k2 = 0; k2 < 4; ++k2) {
                        float2 f = __half22float2(xs2[k2 * NIC + row]);
                        xv[2 * k2] = f.x; xv[2 * k2 + 1] = f.y;
                    }
                    float bv[NOC], mx = -1e30f;
                    #pragma unroll
                    for (int jj = 0; jj < NOC; ++jj) {
                        const float* up = &Ul[(jj * 32 + ns) * USTR];
                        float4 u0 = *(const float4*)up;
                        float4 u1 = *(const float4*)(up + 4);
                        float bb = up[8]
                            + u0.x*xv[0] + u0.y*xv[1] + u0.z*xv[2] + u0.w*xv[3]
                            + u1.x*xv[4] + u1.y*xv[5] + u1.z*xv[6] + u1.w*xv[7];
                        bv[jj] = bb; mx = fmaxf(mx, bb);
                    }
                    float se = 0.f;
                    #pragma unroll
                    for (int jj = 0; jj < NOC; ++jj) se += __expf(bv[jj] - mx);
                    stat2[row] = mx + __logf(se);
                }
            }
            __syncthreads();
        }

        // ---- Phase B: t[k] = sum_p c*x[k,p]; cs in t[8] (registers) ----
        float t[9];
        #pragma unroll
        for (int kk = 0; kk < 9; ++kk) t[kk] = 0.f;
        if (it == 0) {
            for (int p = 0; p < HW; ++p) {
                int row = p * 32 + ns;
                #pragma unroll
                for (int k2 = 0; k2 < 4; ++k2) {
                    float2 f = __half22float2(xs2[k2 * NIC + row]);
                    t[2 * k2] += f.x; t[2 * k2 + 1] += f.y;
                }
            }
            #pragma unroll
            for (int kk = 0; kk < 8; ++kk) t[kk] *= 0.1f;
            t[8] = 3.6f;
        } else {
            for (int p = 0; p < HW; ++p) {
                int row = p * 32 + ns;
                float xv[8];
                #pragma unroll
                for (int k2 = 0; k2 < 4; ++k2) {
                    float2 f = __half22float2(xs2[k2 * NIC + row]);
                    xv[2 * k2] = f.x; xv[2 * k2 + 1] = f.y;
                }
                float bb = ua[8]
                    + ua[0]*xv[0] + ua[1]*xv[1] + ua[2]*xv[2] + ua[3]*xv[3]
                    + ua[4]*xv[4] + ua[5]*xv[5] + ua[6]*xv[6] + ua[7]*xv[7];
                float c = __expf(bb - stat2[row]);
                #pragma unroll
                for (int kk = 0; kk < 8; ++kk) t[kk] += c * xv[kk];
                t[8] += c;
            }
        }

        // ---- Phase C: ps[d] = W16[r,:]·t + bcv[d]*cs; butterfly over ns ----
        float ps[16];
        #pragma unroll
        for (int d = 0; d < OD; ++d) {
            uint4 wv = *(const uint4*)(wrow + (size_t)d * 8);   // 8 halfs, 16 B
            float2 w0 = __half22float2(*(__half2*)&wv.x);
            float2 w1 = __half22float2(*(__half2*)&wv.y);
            float2 w2 = __half22float2(*(__half2*)&wv.z);
            float2 w3 = __half22float2(*(__half2*)&wv.w);
            ps[d] = w0.x*t[0] + w0.y*t[1] + w1.x*t[2] + w1.y*t[3]
                  + w2.x*t[4] + w2.y*t[5] + w3.x*t[6] + w3.y*t[7]
                  + bcv[d] * t[8];
        }
        #pragma unroll
        for (int mk = 1; mk < 32; mk <<= 1) {
            #pragma unroll
            for (int d = 0; d < OD; ++d)
                ps[d] += __shfl_xor(ps[d], mk, 64);
        }
        float ss = 0.f;
        #pragma unroll
        for (int d = 0; d < OD; ++d) ss += ps[d] * ps[d];
        float fc = sqrtf(ss) / (1.f + ss);

        if (it == ROUTE - 1) {
            if (ns == 0) {
                float4* o = (float4*)(out + (size_t)blockIdx.x * (NOC * OD) + j * OD);
                o[0] = make_float4(ps[0]*fc,  ps[1]*fc,  ps[2]*fc,  ps[3]*fc);
                o[1] = make_float4(ps[4]*fc,  ps[5]*fc,  ps[6]*fc,  ps[7]*fc);
                o[2] = make_float4(ps[8]*fc,  ps[9]*fc,  ps[10]*fc, ps[11]*fc);
                o[3] = make_float4(ps[12]*fc, ps[13]*fc, ps[14]*fc, ps[15]*fc);
            }
            break;
        }

        // ---- Phase D: u[k] = sum_d v[d]*W16[r,k]; ua += u; mirror to Ul ----
        float u[9];
        #pragma unroll
        for (int kk = 0; kk < 9; ++kk) u[kk] = 0.f;
        #pragma unroll
        for (int d = 0; d < OD; ++d) {
            float vv = ps[d] * fc;
            uint4 wv = *(const uint4*)(wrow + (size_t)d * 8);
            float2 w0 = __half22float2(*(__half2*)&wv.x);
            float2 w1 = __half22float2(*(__half2*)&wv.y);
            float2 w2 = __half22float2(*(__half2*)&wv.z);
            float2 w3 = __half22float2(*(__half2*)&wv.w);
            u[0] += vv*w0.x; u[1] += vv*w0.y; u[2] += vv*w1.x; u[3] += vv*w1.y;
            u[4] += vv*w2.x; u[5] += vv*w2.y; u[6] += vv*w3.x; u[7] += vv*w3.y;
            u[8] += vv*bcv[d];
        }
        if (it == 0) {
            #pragma unroll
            for (int kk = 0; kk < 9; ++kk) ua[kk] = u[kk];
        } else {
            #pragma unroll
            for (int kk = 0; kk < 9; ++kk) ua[kk] += u[kk];
        }
        {
            float* up = &Ul[(j * 32 + ns) * USTR];
            *(float4*)up       = make_float4(ua[0], ua[1], ua[2], ua[3]);
            *(float4*)(up + 4) = make_float4(ua[4], ua[5], ua[6], ua[7]);
            up[8] = ua[8];
        }
        __syncthreads();
    }
}

extern "C" void kernel_launch(void* const* d_in, const int* in_sizes, int n_in,
                              void* d_out, int out_size, void* d_ws, size_t ws_size,
                              hipStream_t stream) {
    const float* x  = (const float*)d_in[0];
    // d_in[1] = target (int32) — unused in forward
    const float* Wc = (const float*)d_in[2];
    const float* bc = (const float*)d_in[3];
    float* out = (float*)d_out;

    __half* w16 = (__half*)d_ws;        // 40960 W halfs + 5120 bias halfs = 92160 B
    convert_w<<<dim3(48), dim3(256), 0, stream>>>(Wc, bc, w16);
    caps_kernel<<<dim3(BSZ), dim3(NT), 0, stream>>>(x, w16, w16 + 40960, out);
}